// Round 11
// baseline (546.641 us; speedup 1.0000x reference)
//
#include <hip/hip_runtime.h>
#include <hip/hip_bf16.h>
#include <hip/hip_fp16.h>
#include <cmath>

// CrAKN fused implementation.
// R20 = R19 + oproj(l) for l=0..2 folded into bias(l+1)'s prologue
// (combine split-m partials -> o-proj -> LN2 -> s_x -> qkv), with x
// ping-pong buffers to avoid writer/reader races across the 8 blocks
// sharing a row-pair. Final oproj (l=3) stays standalone (dofinal).
// Dispatches 14 -> 11. Math identical except o-dot summation order
// (halves vs quarters, ~1e-6 fp32 reorder).

namespace {

constexpr int kN   = 512;
constexpr int kD   = 64;
constexpr int kH   = 4;
constexpr int kHD  = 128;
constexpr int kHHD = 512;
constexpr int kFB  = 256;
constexpr int kK   = 100;
constexpr float kEps   = 1e-5f;
constexpr float kScale = 0.08838834764831845f; // 1/sqrt(128)

typedef unsigned short u16;
typedef unsigned int u32;
typedef short bf16x8 __attribute__((ext_vector_type(8)));   // raw 16B container
typedef _Float16 f16x8 __attribute__((ext_vector_type(8)));
typedef float f32x4 __attribute__((ext_vector_type(4)));
typedef float f32x2 __attribute__((ext_vector_type(2)));

// packed-pair mish: identical math per lane; non-trans ops on f32x2 so the
// compiler can select v_pk_add_f32 / v_pk_fma_f32 (VOP3P, gfx90a+).
__device__ __forceinline__ f32x2 mish2(f32x2 x) {
    float e0 = __expf(x[0]);
    float e1 = __expf(x[1]);
    f32x2 e  = {e0, e1};
    f32x2 n2 = __builtin_elementwise_fma(e, e + 2.0f, (f32x2)(2.0f));
    f32x2 r  = {__builtin_amdgcn_rcpf(n2[0]), __builtin_amdgcn_rcpf(n2[1])};
    return __builtin_elementwise_fma(x + x, -r, x);
}

__device__ __forceinline__ u32 pkh(float a, float b) {
    union { __half2 h; u32 u; } cv;
    cv.h = __float22half2_rn(make_float2(a, b));
    return cv.u; // a low 16, b high 16
}
__device__ __forceinline__ f16x8 mkh8(u32 a, u32 b, u32 c, u32 d) {
    union { u32 w[4]; f16x8 v; } cv;
    cv.w[0] = a; cv.w[1] = b; cv.w[2] = c; cv.w[3] = d;
    return cv.v;
}
__device__ __forceinline__ u16 f16_bits(float f) {
    union { __half h; u16 u; } cv;
    cv.h = __float2half(f);
    return cv.u;
}

__device__ __forceinline__ float dot4(float4 a, float4 b, float acc) {
    acc = fmaf(a.x, b.x, acc);
    acc = fmaf(a.y, b.y, acc);
    acc = fmaf(a.z, b.z, acc);
    acc = fmaf(a.w, b.w, acc);
    return acc;
}
__device__ __forceinline__ float4 fma4(float s, float4 v, float4 d) {
    d.x = fmaf(s, v.x, d.x);
    d.y = fmaf(s, v.y, d.y);
    d.z = fmaf(s, v.z, d.z);
    d.w = fmaf(s, v.w, d.w);
    return d;
}

// ---------------- embed + LN1, and b0 = amds @ bias_emb ----------------
__global__ __launch_bounds__(64) void embed_kernel(
    const float* __restrict__ nf, const float* __restrict__ amds,
    const float* __restrict__ emb_W, const float* __restrict__ emb_b,
    const float* __restrict__ bemb_W, const float* __restrict__ bemb_b,
    const float* __restrict__ ln1_g, const float* __restrict__ ln1_b,
    float* __restrict__ x, float* __restrict__ b0)
{
    const int n = blockIdx.x;
    const int d = threadIdx.x;
    __shared__ float s_row[kFB];
    #pragma unroll
    for (int r = 0; r < kFB / kD; ++r) s_row[r * kD + d] = nf[n * kFB + r * kD + d];
    __syncthreads();
    float acc = emb_b[d];
    for (int k = 0; k < kFB; ++k) acc = fmaf(s_row[k], emb_W[k * kD + d], acc);
    float mu = acc;
    #pragma unroll
    for (int off = 32; off > 0; off >>= 1) mu += __shfl_xor(mu, off);
    mu *= (1.0f / kD);
    float dv = acc - mu;
    float var = dv * dv;
    #pragma unroll
    for (int off = 32; off > 0; off >>= 1) var += __shfl_xor(var, off);
    var *= (1.0f / kD);
    x[n * kD + d] = dv * rsqrtf(var + kEps) * ln1_g[d] + ln1_b[d];
    __syncthreads();
    s_row[d] = amds[n * kK + d];
    if (d < kK - kD) s_row[kD + d] = amds[n * kK + kD + d];
    __syncthreads();
    float bacc = bemb_b[d];
    for (int k = 0; k < kK; ++k) bacc = fmaf(s_row[k], bemb_W[k * kD + d], bacc);
    b0[n * kD + d] = bacc;
}

// ---------------- per-launch weight prep: transpose + fp16 ----------------
__global__ __launch_bounds__(256) void prep_weights_kernel(
    const float* __restrict__ diff_W, const float* __restrict__ bout_W,
    u16* __restrict__ dWt, u16* __restrict__ boutWt)
{
    int gid = blockIdx.x * 256 + threadIdx.x; // 2 * 4 * 32768
    if (gid < 4 * 32768) {
        int e = gid;
        int l = e >> 15;
        int r = e & 32767;
        int k = r >> 9;
        int n = r & 511;
        dWt[l * 32768 + n * 64 + k] = f16_bits(diff_W[e]);
    } else {
        int e = gid - 4 * 32768;
        int l = e >> 15;
        int r = e & 32767;
        int k = r >> 6;
        int d = r & 63;
        boutWt[l * 32768 + d * 512 + k] = f16_bits(bout_W[e]);
    }
}

// ---------------- fused pair-bias chain, fp16 MFMA + oproj/qkv prologue ----
// R19 structure + (comb) prologue that finishes the PREVIOUS layer's
// attention: combine split-m partials (exact rescale), o-projection,
// LN2 -> s_x (consumed by the qkv prologue) ; one block per row-pair
// writes x to x_out (ping-pong buffer vs x_in to avoid races).
__global__ __launch_bounds__(256, 2) void bias_layer_mfma(
    u16* __restrict__ bias,
    const u16* __restrict__ dWt, const u16* __restrict__ boutWt,
    const float* __restrict__ diff_b, const float* __restrict__ bout_b,
    const float* __restrict__ b0, float* __restrict__ diffs,
    const float* __restrict__ x_in, float* __restrict__ x_out,
    const float* __restrict__ qW, const float* __restrict__ qb,
    float* __restrict__ qkv,
    const float* __restrict__ part, const float* __restrict__ ml,
    const float* __restrict__ oW, const float* __restrict__ ob,
    const float* __restrict__ g2ln, const float* __restrict__ b2ln,
    int last, int first, int comb)
{
    // [buf][ w1: 32 rows * 64 u16 | w2 at 2048: 64 rows * 32 u16 ]
    __shared__ u16 s_w[2][4096]; // 16 KB
    __shared__ float s_db[kHHD]; // 2 KB, broadcast-read per g2
    __shared__ float s_x[2 * kD]; // 512 B, fused-qkv x rows
    __shared__ float s_v[2][kHHD];   // 4 KB, combined attention vals
    __shared__ float s_part[4][kD];  // 1 KB, o-proj half-dots

    const int t    = threadIdx.x;
    const int w    = t >> 6;
    const int lane = t & 63;
    const int q    = lane >> 4;    // quad
    const int c    = lane & 15;
    const int pb   = blockIdx.x * 128 + w * 32;  // wave's 32 pairs
    const int n0r  = (blockIdx.x >> 3) * 2;      // fused rows n0r, n0r+1

    const int sb_bc  = t >> 3;
    const int sb_kb  = t & 7;
    const int sr     = ((sb_bc >> 2) & 1) * 16 + ((sb_bc >> 3) << 2) + (sb_bc & 3);
    const int w1_dst = sr * 64 + (sb_kb ^ (sr & 7)) * 8;
    const int sb_d   = t >> 2;
    const int sb_k2  = t & 3;
    const int w2_dst = 2048 + sb_d * 32 + (sb_k2 ^ ((sb_d >> 1) & 3)) * 8;
    const u16* g_w1 = dWt + sb_bc * 64 + sb_kb * 8;
    const u16* g_w2 = boutWt + sb_d * 512 + sb_k2 * 8;

    // --- B-frags: bias^T (fp16) for two 16-pair tiles, K=64.
    f16x8 Bf[2][2];
    if (first) {
        const int ii = pb >> 9;                   // block-uniform i
        const float* bi = b0 + ii * kD;
        #pragma unroll
        for (int mt = 0; mt < 2; ++mt) {
            const int jj = (pb & 511) + mt * 16 + c;
            const float* bj = b0 + jj * kD;
            #pragma unroll
            for (int s = 0; s < 2; ++s) {
                const int d0 = s * 32 + q * 8;
                float4 a0 = *(const float4*)(bj + d0);
                float4 a1v = *(const float4*)(bj + d0 + 4);
                float4 c0 = *(const float4*)(bi + d0);
                float4 c1v = *(const float4*)(bi + d0 + 4);
                Bf[mt][s] = mkh8(pkh(a0.x - c0.x, a0.y - c0.y),
                                 pkh(a0.z - c0.z, a0.w - c0.w),
                                 pkh(a1v.x - c1v.x, a1v.y - c1v.y),
                                 pkh(a1v.z - c1v.z, a1v.w - c1v.w));
            }
        }
    } else {
        #pragma unroll
        for (int mt = 0; mt < 2; ++mt) {
            #pragma unroll
            for (int s = 0; s < 2; ++s) {
                Bf[mt][s] = *(const f16x8*)(bias + (long)(pb + mt * 16 + c) * kD + s * 32 + q * 8);
            }
        }
    }

    {
        bf16x8 r0 = *(const bf16x8*)g_w1;
        bf16x8 r1 = *(const bf16x8*)g_w2;
        *(bf16x8*)&s_w[0][w1_dst] = r0;
        *(bf16x8*)&s_w[0][w2_dst] = r1;
        s_db[t] = diff_b[t];
        s_db[256 + t] = diff_b[256 + t];
    }

    if (comb) {
        // ---- finish previous layer's attention for rows n0r, n0r+1 ----
        // (1) combine split-m partials (exact softmax rescale)
        #pragma unroll
        for (int p = t; p < 1024; p += 256) {
            const int row = p >> 9;
            const int j   = p & 511;
            const int hh  = j >> 7;
            const int dd  = j & 127;
            const int n   = n0r + row;
            float2 m_l[4];
            float M = -1e30f;
            #pragma unroll
            for (int qq = 0; qq < 4; ++qq) {
                m_l[qq] = *(const float2*)&ml[((hh * 4 + qq) * kN + n) * 2];
                M = fmaxf(M, m_l[qq].x);
            }
            float L = 0.0f, wq[4];
            #pragma unroll
            for (int qq = 0; qq < 4; ++qq) {
                wq[qq] = __expf(m_l[qq].x - M);
                L = fmaf(wq[qq], m_l[qq].y, L);
            }
            float sv = 0.0f;
            #pragma unroll
            for (int qq = 0; qq < 4; ++qq)
                sv = fmaf(wq[qq], part[(hh * 4 + qq) * (kN * kHD) + n * kHD + dd], sv);
            s_v[row][j] = sv / L;
        }
        __syncthreads();
        // (2) o-projection: wave w handles (row = w>>1, half = w&1)
        {
            const int d = t & 63, row = w >> 1, half = w & 1;
            float acc = 0.0f;
            const float* vp = &s_v[row][half * 256];
            const float* wp = oW + (half * 256) * kD + d;
            #pragma unroll 4
            for (int j = 0; j < 256; ++j)
                acc = fmaf(vp[j], wp[j * kD], acc);
            s_part[w][d] = acc;
        }
        __syncthreads();
        // (3) LN2 -> s_x ; one block per row-pair persists x
        {
            const int d = t & 63;
            if ((w & 1) == 0) {
                const int r2 = w >> 1;
                const int n = n0r + r2;
                float av = ob[d] + (s_part[w][d] + s_part[w + 1][d]);
                float xv = x_in[n * kD + d] + av;
                float mu = xv;
                #pragma unroll
                for (int off = 32; off > 0; off >>= 1) mu += __shfl_xor(mu, off);
                mu *= (1.0f / kD);
                float dv = xv - mu;
                float var = dv * dv;
                #pragma unroll
                for (int off = 32; off > 0; off >>= 1) var += __shfl_xor(var, off);
                var *= (1.0f / kD);
                float xnew = dv * rsqrtf(var + kEps) * g2ln[d] + b2ln[d];
                s_x[r2 * kD + d] = xnew;
                if ((blockIdx.x & 7) == 0) x_out[n * kD + d] = xnew;
            }
        }
        __syncthreads();
    } else {
        if (t < 2 * kD) s_x[t] = x_in[n0r * kD + t];
        __syncthreads();
    }

    // ---- fused qkv: 2 rows x 192 cols; independent of the g2 loop below.
    if (t < 192) {
        const int cc = (blockIdx.x & 7) * 192 + t;
        float a0 = qb[cc];
        float a1 = a0;
        #pragma unroll 8
        for (int k = 0; k < kD; ++k) {
            float wv = qW[k * (3 * kHHD) + cc];
            a0 = fmaf(s_x[k], wv, a0);
            a1 = fmaf(s_x[kD + k], wv, a1);
        }
        qkv[n0r * (3 * kHHD) + cc] = a0;
        qkv[(n0r + 1) * (3 * kHHD) + cc] = a1;
    }

    f32x4 acc2[2][4];
    #pragma unroll
    for (int mt = 0; mt < 2; ++mt)
        #pragma unroll
        for (int dg = 0; dg < 4; ++dg) acc2[mt][dg] = (f32x4)0.0f;
    f32x2 psum2[2][4];
    #pragma unroll
    for (int mt = 0; mt < 2; ++mt)
        #pragma unroll
        for (int h = 0; h < 4; ++h) psum2[mt][h] = (f32x2)0.0f;

    const int sw1 = c & 7;
    const int sw2 = (c >> 1) & 3;
    int cur = 0;

    for (int g2 = 0; g2 < 16; ++g2) {
        bf16x8 r0, r1;
        if (g2 < 15) {
            r0 = *(const bf16x8*)(g_w1 + (g2 + 1) * 2048);
            r1 = *(const bf16x8*)(g_w2 + (g2 + 1) * 32);
        }

        // ---- GEMM1 with C initialized to diff_b
        const f32x4 db4l = *(const f32x4*)&s_db[g2 * 32 + q * 8];      // u=0
        const f32x4 db4h = *(const f32x4*)&s_db[g2 * 32 + q * 8 + 4];  // u=1
        f32x4 a1[2][2];
        #pragma unroll
        for (int mt = 0; mt < 2; ++mt) {
            a1[mt][0] = db4l;
            a1[mt][1] = db4h;
        }
        const u16* w1 = &s_w[cur][0];
        #pragma unroll
        for (int u = 0; u < 2; ++u) {
            int row = (u * 16 + c) * 64;
            int o0 = row + ((0 + q) ^ sw1) * 8;
            int o1 = row + ((4 + q) ^ sw1) * 8;
            f16x8 A0 = *(const f16x8*)(w1 + o0);
            f16x8 A1 = *(const f16x8*)(w1 + o1);
            #pragma unroll
            for (int mt = 0; mt < 2; ++mt) {
                a1[mt][u] = __builtin_amdgcn_mfma_f32_16x16x32_f16(A0, Bf[mt][0], a1[mt][u], 0, 0, 0);
                a1[mt][u] = __builtin_amdgcn_mfma_f32_16x16x32_f16(A1, Bf[mt][1], a1[mt][u], 0, 0, 0);
            }
        }

        // ---- mish + psum + fp16 pack (packed-fp32 pairs; db already in a1)
        const int hd = g2 >> 2;
        f16x8 A2[2];
        #pragma unroll
        for (int mt = 0; mt < 2; ++mt) {
            u32 p[2][2];
            #pragma unroll
            for (int u = 0; u < 2; ++u) {
                f32x2 xlo = {a1[mt][u][0], a1[mt][u][1]};
                f32x2 xhi = {a1[mt][u][2], a1[mt][u][3]};
                f32x2 vlo = mish2(xlo);
                f32x2 vhi = mish2(xhi);
                psum2[mt][hd] = __builtin_elementwise_fma(vlo, vlo, psum2[mt][hd]);
                psum2[mt][hd] = __builtin_elementwise_fma(vhi, vhi, psum2[mt][hd]);
                p[u][0] = pkh(vlo[0], vlo[1]);
                p[u][1] = pkh(vhi[0], vhi[1]);
            }
            A2[mt] = mkh8(p[0][0], p[0][1], p[1][0], p[1][1]);
        }

        if (!last) {
            const u16* w2 = &s_w[cur][2048];
            const int kb2 = (q ^ sw2) * 8;
            #pragma unroll
            for (int dg = 0; dg < 4; ++dg) {
                int bo = dg * 512 + c * 32 + kb2;
                f16x8 Wf = *(const f16x8*)(w2 + bo);
                #pragma unroll
                for (int mt = 0; mt < 2; ++mt) {
                    acc2[mt][dg] = __builtin_amdgcn_mfma_f32_16x16x32_f16(A2[mt], Wf, acc2[mt][dg], 0, 0, 0);
                }
            }
        }

        if (g2 < 15) {
            int nb = cur ^ 1;
            *(bf16x8*)&s_w[nb][w1_dst] = r0;
            *(bf16x8*)&s_w[nb][w2_dst] = r1;
            __syncthreads();
            cur = nb;
        }
    }

    // ---- epilogue: bias tile in place (fp16) + diffs
    if (!last) {
        #pragma unroll
        for (int mt = 0; mt < 2; ++mt) {
            #pragma unroll
            for (int dg = 0; dg < 4; ++dg) {
                float bb = bout_b[dg * 16 + c];
                f32x2 bb2 = {bb, bb};
                f32x2 vlo = mish2(f32x2{acc2[mt][dg][0], acc2[mt][dg][1]} + bb2);
                f32x2 vhi = mish2(f32x2{acc2[mt][dg][2], acc2[mt][dg][3]} + bb2);
                const long rbase = (long)(pb + mt * 16 + 4 * q);
                bias[(rbase + 0) * kD + dg * 16 + c] = f16_bits(vlo[0]);
                bias[(rbase + 1) * kD + dg * 16 + c] = f16_bits(vlo[1]);
                bias[(rbase + 2) * kD + dg * 16 + c] = f16_bits(vhi[0]);
                bias[(rbase + 3) * kD + dg * 16 + c] = f16_bits(vhi[1]);
            }
        }
    }
    const int i  = blockIdx.x >> 2;
    const int jb = (blockIdx.x & 3) * 128 + w * 32;
    #pragma unroll
    for (int mt = 0; mt < 2; ++mt) {
        float psum[4];
        #pragma unroll
        for (int h = 0; h < 4; ++h) {
            psum[h] = psum2[mt][h][0] + psum2[mt][h][1];
            psum[h] += __shfl_xor(psum[h], 16);
            psum[h] += __shfl_xor(psum[h], 32);
        }
        float sv = (q == 0) ? psum[0] : (q == 1) ? psum[1]
                 : (q == 2) ? psum[2] : psum[3];
        diffs[q * (kN * kN) + i * kN + jb + mt * 16 + c] = sqrtf(sv);
    }
}

// ---------------- fused flash attention (split-m, exact) ----------------
// grid (16 n-tiles of 32 rows, 4 m-chunks of 128, 4 heads) = 256 blocks.
// 512 threads (8 waves = 2 waves/SIMD at 1 block/CU).
__global__ __launch_bounds__(512) void flash_attn_kernel(
    const float* __restrict__ qkv, const float* __restrict__ diffs,
    float* __restrict__ part, float* __restrict__ ml)
{
    __shared__ float s_a[32 * 132];  // Q (QK phase), then P (PV phase)
    __shared__ float s_b[128 * 36];  // K chunks; then V chunks (32*132 fits)

    const int t  = threadIdx.x;
    const int tx = t & 31;
    const int ty = t >> 5;          // 0..15
    const int r0 = ty * 2;          // rows r0, r0+1
    const int n0 = blockIdx.x * 32;
    const int mq = blockIdx.y;
    const int h  = blockIdx.z;
    const int m0 = mq * 128;

    // ---- stage Q (32 x 128) : 1024 float4 over 512 threads
    #pragma unroll
    for (int rep = 0; rep < 2; ++rep) {
        int f = rep * 512 + t;
        int row = f >> 5;
        int c4  = f & 31;
        *(float4*)&s_a[row * 132 + c4 * 4] =
            *(const float4*)&qkv[(n0 + row) * (3 * kHHD) + h * 384 + c4 * 4];
    }

    float acc[2][4];
    #pragma unroll
    for (int i = 0; i < 2; ++i)
        #pragma unroll
        for (int cc = 0; cc < 4; ++cc) acc[i][cc] = 0.0f;

    // ---- S = Q K^T, k-dim chunked by 32
    for (int db = 0; db < 4; ++db) {
        __syncthreads();
        #pragma unroll
        for (int rep = 0; rep < 2; ++rep) {
            int f = rep * 512 + t;
            int col = f >> 3;
            int c4  = f & 7;
            *(float4*)&s_b[col * 36 + c4 * 4] =
                *(const float4*)&qkv[(m0 + col) * (3 * kHHD) + h * 384 + 128 + db * 32 + c4 * 4];
        }
        __syncthreads();
        #pragma unroll
        for (int k4 = 0; k4 < 8; ++k4) {
            float4 a0 = *(const float4*)&s_a[(r0 + 0) * 132 + db * 32 + k4 * 4];
            float4 a1 = *(const float4*)&s_a[(r0 + 1) * 132 + db * 32 + k4 * 4];
            #pragma unroll
            for (int cc = 0; cc < 4; ++cc) {
                float4 b = *(const float4*)&s_b[(tx + 32 * cc) * 36 + k4 * 4];
                acc[0][cc] = dot4(a0, b, acc[0][cc]);
                acc[1][cc] = dot4(a1, b, acc[1][cc]);
            }
        }
    }

    // ---- logits = S*scale + diffs; per-row softmax partial over 128 cols
    float mr[2], lr[2];
    #pragma unroll
    for (int i = 0; i < 2; ++i) {
        const float* dro = diffs + h * (kN * kN) + (n0 + r0 + i) * kN + m0 + tx;
        #pragma unroll
        for (int cc = 0; cc < 4; ++cc)
            acc[i][cc] = fmaf(acc[i][cc], kScale, dro[32 * cc]);
        float m = fmaxf(fmaxf(acc[i][0], acc[i][1]), fmaxf(acc[i][2], acc[i][3]));
        #pragma unroll
        for (int off = 1; off < 32; off <<= 1) m = fmaxf(m, __shfl_xor(m, off));
        mr[i] = m;
        float l = 0.0f;
        #pragma unroll
        for (int cc = 0; cc < 4; ++cc) {
            float p = __expf(acc[i][cc] - m);
            acc[i][cc] = p;
            l += p;
        }
        #pragma unroll
        for (int off = 1; off < 32; off <<= 1) l += __shfl_xor(l, off);
        lr[i] = l;
    }

    __syncthreads();   // all QK reads of s_a/s_b complete before overwrite
    #pragma unroll
    for (int i = 0; i < 2; ++i) {
        #pragma unroll
        for (int cc = 0; cc < 4; ++cc)
            s_a[(r0 + i) * 132 + tx + 32 * cc] = acc[i][cc];
        if (tx == 0)
            *(float2*)&ml[((h * 4 + mq) * kN + n0 + r0 + i) * 2] = make_float2(mr[i], lr[i]);
    }

    // ---- part = P V, m chunked by 32; V staged [m][d] (float4 reads)
    float4 o0 = {0,0,0,0}, o1 = {0,0,0,0};
    for (int ms = 0; ms < 4; ++ms) {
        if (ms > 0) __syncthreads();  // prior PV reads of s_b done
        #pragma unroll
        for (int rep = 0; rep < 2; ++rep) {
            int f = rep * 512 + t;
            int row = f >> 5;
            int c4  = f & 31;
            *(float4*)&s_b[row * 132 + c4 * 4] =
                *(const float4*)&qkv[(m0 + ms * 32 + row) * (3 * kHHD) + h * 384 + 256 + c4 * 4];
        }
        __syncthreads();  // V staged; (ms==0: P stores also visible)
        #pragma unroll
        for (int k4 = 0; k4 < 8; ++k4) {
            float4 p0 = *(const float4*)&s_a[(r0 + 0) * 132 + ms * 32 + k4 * 4];
            float4 p1 = *(const float4*)&s_a[(r0 + 1) * 132 + ms * 32 + k4 * 4];
            #pragma unroll
            for (int u = 0; u < 4; ++u) {
                float4 v = *(const float4*)&s_b[(k4 * 4 + u) * 132 + tx * 4];
                float pu0 = (u == 0) ? p0.x : (u == 1) ? p0.y : (u == 2) ? p0.z : p0.w;
                float pu1 = (u == 0) ? p1.x : (u == 1) ? p1.y : (u == 2) ? p1.z : p1.w;
                o0 = fma4(pu0, v, o0);
                o1 = fma4(pu1, v, o1);
            }
        }
    }
    const int pbase = (h * 4 + mq) * (kN * kHD) + (n0 + r0) * kHD + 4 * tx;
    *(float4*)&part[pbase]       = o0;
    *(float4*)&part[pbase + kHD] = o1;
}

// ---------------- x = LN2(x + combine(part)@o_W + o_b) [+ final] ----------
// Only launched for the last layer now (dofinal=1).
__global__ __launch_bounds__(256) void oproj_ln_kernel(
    const float* __restrict__ part, const float* __restrict__ ml,
    const float* __restrict__ o_W, const float* __restrict__ o_b,
    const float* __restrict__ g2, const float* __restrict__ b2,
    float* __restrict__ x,
    const float* __restrict__ out_W, const float* __restrict__ out_b,
    float* __restrict__ out, int dofinal)
{
    const int n = blockIdx.x;
    const int t = threadIdx.x;
    const int w = t >> 6;
    const int d = t & 63;
    __shared__ float s_v[kHHD];
    __shared__ float s_part[4][kD];
    #pragma unroll
    for (int r = 0; r < 2; ++r) {
        int j  = r * 256 + t;
        int h  = j >> 7;
        int dd = j & 127;
        float2 m_l[4];
        float M = -1e30f;
        #pragma unroll
        for (int q = 0; q < 4; ++q) {
            m_l[q] = *(const float2*)&ml[((h * 4 + q) * kN + n) * 2];
            M = fmaxf(M, m_l[q].x);
        }
        float L = 0.0f, wq[4];
        #pragma unroll
        for (int q = 0; q < 4; ++q) {
            wq[q] = __expf(m_l[q].x - M);
            L = fmaf(wq[q], m_l[q].y, L);
        }
        float sv = 0.0f;
        #pragma unroll
        for (int q = 0; q < 4; ++q) {
            sv = fmaf(wq[q], part[(h * 4 + q) * (kN * kHD) + n * kHD + dd], sv);
        }
        s_v[j] = sv / L;
    }
    __syncthreads();
    float acc = 0.0f;
    #pragma unroll 4
    for (int j = 0; j < 128; ++j)
        acc = fmaf(s_v[w * 128 + j], o_W[(w * 128 + j) * kD + d], acc);
    s_part[w][d] = acc;
    __syncthreads();
    if (t < kD) {
        float av = o_b[d] + ((s_part[0][d] + s_part[1][d]) + (s_part[2][d] + s_part[3][d]));
        float xv = x[n * kD + d] + av;
        float mu = xv;
        #pragma unroll
        for (int off = 32; off > 0; off >>= 1) mu += __shfl_xor(mu, off);
        mu *= (1.0f / kD);
        float dv = xv - mu;
        float var = dv * dv;
        #pragma unroll
        for (int off = 32; off > 0; off >>= 1) var += __shfl_xor(var, off);
        var *= (1.0f / kD);
        float xnew = dv * rsqrtf(var + kEps) * g2[d] + b2[d];
        x[n * kD + d] = xnew;
        if (dofinal) {
            float p = xnew * out_W[d];
            #pragma unroll
            for (int off = 32; off > 0; off >>= 1) p += __shfl_xor(p, off);
            if (d == 0) out[n] = p + out_b[0];
        }
    }
}

} // anonymous namespace

extern "C" void kernel_launch(void* const* d_in, const int* in_sizes, int n_in,
                              void* d_out, int out_size, void* d_ws, size_t ws_size,
                              hipStream_t stream)
{
    (void)in_sizes; (void)n_in; (void)out_size; (void)ws_size;

    const float* nf     = (const float*)d_in[0];
    const float* amds   = (const float*)d_in[1];
    const float* emb_W  = (const float*)d_in[2];
    const float* emb_b  = (const float*)d_in[3];
    const float* bemb_W = (const float*)d_in[4];
    const float* bemb_b = (const float*)d_in[5];
    const float* ln1_g  = (const float*)d_in[6];
    const float* ln1_b  = (const float*)d_in[7];
    const float* ln2_g  = (const float*)d_in[8];
    const float* ln2_b  = (const float*)d_in[9];
    const float* qkv_W  = (const float*)d_in[10];
    const float* qkv_b  = (const float*)d_in[11];
    const float* diff_W = (const float*)d_in[12];
    const float* diff_b = (const float*)d_in[13];
    const float* o_W    = (const float*)d_in[14];
    const float* o_b    = (const float*)d_in[15];
    const float* bout_W = (const float*)d_in[16];
    const float* bout_b = (const float*)d_in[17];
    const float* out_W  = (const float*)d_in[18];
    const float* out_b  = (const float*)d_in[19];

    float* ws = (float*)d_ws;
    float* ws_x      = ws;                   // 512*64  (x buffer A)
    float* ws_b0     = ws_x + 32768;         // 512*64
    float* ws_qkv    = ws_b0 + 32768;        // 512*1536
    float* ws_ml     = ws_qkv + 786432;      // ml uses [0,16384)
    float* ws_x2     = ws_ml + 131072;       // x buffer B (inside old slot)
    float* ws_diffs  = ws_ml + 262144;       // 4*512*512 (diffs)
    float* ws_part   = ws_diffs + 1048576;   // 4h*4mq*512*128 fp32 = 4 MB
    u16*   ws_bias   = (u16*)(ws_part + 1048576); // 512*512*64 fp16 (33.5 MB)
    u16*   dWt       = ws_bias + 16777216;   // 4*512*64  fp16
    u16*   boutWt    = dWt + 131072;         // 4*64*512  fp16

    embed_kernel<<<kN, kD, 0, stream>>>(nf, amds, emb_W, emb_b, bemb_W, bemb_b,
                                        ln1_g, ln1_b, ws_x, ws_b0);
    prep_weights_kernel<<<(2 * 4 * 32768) / 256, 256, 0, stream>>>(
        diff_W, bout_W, dWt, boutWt);

    float* xbuf[2] = {ws_x, ws_x2};
    for (int l = 0; l < 4; ++l) {
        // x(l-1) residual / x(l) output ping-pong:
        // l=0 reads A (embed); l=1 reads A writes B; l=2 reads B writes A;
        // l=3 reads A writes B; final oproj reads B.
        const float* xin = (l == 0) ? xbuf[0] : xbuf[(l + 1) & 1];
        float* xout = xbuf[l & 1];
        const int lprev = (l > 0) ? (l - 1) : 0;
        bias_layer_mfma<<<kN * kN / 128, 256, 0, stream>>>(
            ws_bias, dWt + l * 32768, boutWt + l * 32768,
            diff_b + l * kHHD, bout_b + l * kD, ws_b0, ws_diffs,
            xin, xout,
            qkv_W + l * kD * (3 * kHHD), qkv_b + l * (3 * kHHD), ws_qkv,
            ws_part, ws_ml, o_W + lprev * kHHD * kD, o_b + lprev * kD,
            ln2_g, ln2_b,
            (l == 3) ? 1 : 0, (l == 0) ? 1 : 0, (l > 0) ? 1 : 0);
        flash_attn_kernel<<<dim3(16, 4, kH), 512, 0, stream>>>(
            ws_qkv, ws_diffs, ws_part, ws_ml);
    }
    oproj_ln_kernel<<<kN, 256, 0, stream>>>(
        ws_part, ws_ml, o_W + 3 * kHHD * kD, o_b + 3 * kD, ln2_g, ln2_b, xbuf[1],
        out_W, out_b, (float*)d_out, 1);
}

// Round 12
// 483.299 us; speedup vs baseline: 1.1311x; 1.1311x over previous
//
#include <hip/hip_runtime.h>
#include <hip/hip_bf16.h>
#include <hip/hip_fp16.h>
#include <cmath>

// CrAKN fused implementation.
// R21 = R19 (reverted R20's oproj-fusion regression: prologue serialization
// +40us > dispatch savings ~10us) + (a) embed+prep merged into one
// setup_kernel (-1 dispatch), (b) flash K/V staged in 2x-bigger LDS chunks
// (K: 2x[128][64] stride 68; V: 2x[64][132]) halving barrier count 16->8;
// LDS 35->50.5 KB, still 1 block/CU (grid-limited). Same math throughout.

namespace {

constexpr int kN   = 512;
constexpr int kD   = 64;
constexpr int kH   = 4;
constexpr int kHD  = 128;
constexpr int kHHD = 512;
constexpr int kFB  = 256;
constexpr int kK   = 100;
constexpr float kEps   = 1e-5f;
constexpr float kScale = 0.08838834764831845f; // 1/sqrt(128)

typedef unsigned short u16;
typedef unsigned int u32;
typedef short bf16x8 __attribute__((ext_vector_type(8)));   // raw 16B container
typedef _Float16 f16x8 __attribute__((ext_vector_type(8)));
typedef float f32x4 __attribute__((ext_vector_type(4)));
typedef float f32x2 __attribute__((ext_vector_type(2)));

// packed-pair mish: identical math per lane; non-trans ops on f32x2 so the
// compiler can select v_pk_add_f32 / v_pk_fma_f32 (VOP3P, gfx90a+).
__device__ __forceinline__ f32x2 mish2(f32x2 x) {
    float e0 = __expf(x[0]);
    float e1 = __expf(x[1]);
    f32x2 e  = {e0, e1};
    f32x2 n2 = __builtin_elementwise_fma(e, e + 2.0f, (f32x2)(2.0f));
    f32x2 r  = {__builtin_amdgcn_rcpf(n2[0]), __builtin_amdgcn_rcpf(n2[1])};
    return __builtin_elementwise_fma(x + x, -r, x);
}

__device__ __forceinline__ u32 pkh(float a, float b) {
    union { __half2 h; u32 u; } cv;
    cv.h = __float22half2_rn(make_float2(a, b));
    return cv.u; // a low 16, b high 16
}
__device__ __forceinline__ f16x8 mkh8(u32 a, u32 b, u32 c, u32 d) {
    union { u32 w[4]; f16x8 v; } cv;
    cv.w[0] = a; cv.w[1] = b; cv.w[2] = c; cv.w[3] = d;
    return cv.v;
}
__device__ __forceinline__ u16 f16_bits(float f) {
    union { __half h; u16 u; } cv;
    cv.h = __float2half(f);
    return cv.u;
}

__device__ __forceinline__ float dot4(float4 a, float4 b, float acc) {
    acc = fmaf(a.x, b.x, acc);
    acc = fmaf(a.y, b.y, acc);
    acc = fmaf(a.z, b.z, acc);
    acc = fmaf(a.w, b.w, acc);
    return acc;
}
__device__ __forceinline__ float4 fma4(float s, float4 v, float4 d) {
    d.x = fmaf(s, v.x, d.x);
    d.y = fmaf(s, v.y, d.y);
    d.z = fmaf(s, v.z, d.z);
    d.w = fmaf(s, v.w, d.w);
    return d;
}

// ---------------- setup: embed+LN1, b0, weight transpose+fp16 ----------------
// blocks [0,512): embed row n (256 threads, work guarded to t<64/t<kK;
// barriers are block-uniform). blocks [512,1536): weight prep.
__global__ __launch_bounds__(256) void setup_kernel(
    const float* __restrict__ nf, const float* __restrict__ amds,
    const float* __restrict__ emb_W, const float* __restrict__ emb_b,
    const float* __restrict__ bemb_W, const float* __restrict__ bemb_b,
    const float* __restrict__ ln1_g, const float* __restrict__ ln1_b,
    float* __restrict__ x, float* __restrict__ b0,
    const float* __restrict__ diff_W, const float* __restrict__ bout_W,
    u16* __restrict__ dWt, u16* __restrict__ boutWt)
{
    const int t = threadIdx.x;
    if (blockIdx.x >= 512) {
        int gid = (blockIdx.x - 512) * 256 + t; // 2 * 4 * 32768
        if (gid < 4 * 32768) {
            int e = gid;
            int l = e >> 15;
            int r = e & 32767;
            int k = r >> 9;
            int n = r & 511;
            dWt[l * 32768 + n * 64 + k] = f16_bits(diff_W[e]);
        } else {
            int e = gid - 4 * 32768;
            int l = e >> 15;
            int r = e & 32767;
            int k = r >> 6;
            int d = r & 63;
            boutWt[l * 32768 + d * 512 + k] = f16_bits(bout_W[e]);
        }
        return;
    }
    const int n = blockIdx.x;
    __shared__ float s_row[kFB];
    s_row[t] = nf[n * kFB + t];
    __syncthreads();
    if (t < kD) {
        const int d = t;
        float acc = emb_b[d];
        for (int k = 0; k < kFB; ++k) acc = fmaf(s_row[k], emb_W[k * kD + d], acc);
        float mu = acc;
        #pragma unroll
        for (int off = 32; off > 0; off >>= 1) mu += __shfl_xor(mu, off);
        mu *= (1.0f / kD);
        float dv = acc - mu;
        float var = dv * dv;
        #pragma unroll
        for (int off = 32; off > 0; off >>= 1) var += __shfl_xor(var, off);
        var *= (1.0f / kD);
        x[n * kD + d] = dv * rsqrtf(var + kEps) * ln1_g[d] + ln1_b[d];
    }
    __syncthreads();
    if (t < kK) s_row[t] = amds[n * kK + t];
    __syncthreads();
    if (t < kD) {
        const int d = t;
        float bacc = bemb_b[d];
        for (int k = 0; k < kK; ++k) bacc = fmaf(s_row[k], bemb_W[k * kD + d], bacc);
        b0[n * kD + d] = bacc;
    }
}

// ---------------- fused pair-bias chain, fp16 MFMA + qkv prologue ----------
// R16 structure (4 waves x 32 pairs, 256 thr, packed-fp32 mish/psum) +
// first-layer Bf from b0 + db-as-accumulator-init + fused qkv for this layer.
__global__ __launch_bounds__(256, 2) void bias_layer_mfma(
    u16* __restrict__ bias,
    const u16* __restrict__ dWt, const u16* __restrict__ boutWt,
    const float* __restrict__ diff_b, const float* __restrict__ bout_b,
    const float* __restrict__ b0, float* __restrict__ diffs,
    const float* __restrict__ x, const float* __restrict__ qW,
    const float* __restrict__ qb, float* __restrict__ qkv,
    int last, int first)
{
    // [buf][ w1: 32 rows * 64 u16 | w2 at 2048: 64 rows * 32 u16 ]
    __shared__ u16 s_w[2][4096]; // 16 KB
    __shared__ float s_db[kHHD]; // 2 KB, broadcast-read per g2
    __shared__ float s_x[2 * kD]; // 512 B, fused-qkv x rows

    const int t    = threadIdx.x;
    const int w    = t >> 6;
    const int lane = t & 63;
    const int q    = lane >> 4;    // quad
    const int c    = lane & 15;
    const int pb   = blockIdx.x * 128 + w * 32;  // wave's 32 pairs

    const int sb_bc  = t >> 3;
    const int sb_kb  = t & 7;
    const int sr     = ((sb_bc >> 2) & 1) * 16 + ((sb_bc >> 3) << 2) + (sb_bc & 3);
    const int w1_dst = sr * 64 + (sb_kb ^ (sr & 7)) * 8;
    const int sb_d   = t >> 2;
    const int sb_k2  = t & 3;
    const int w2_dst = 2048 + sb_d * 32 + (sb_k2 ^ ((sb_d >> 1) & 3)) * 8;
    const u16* g_w1 = dWt + sb_bc * 64 + sb_kb * 8;
    const u16* g_w2 = boutWt + sb_d * 512 + sb_k2 * 8;

    // --- B-frags: bias^T (fp16) for two 16-pair tiles, K=64.
    f16x8 Bf[2][2];
    if (first) {
        const int ii = pb >> 9;                   // block-uniform i
        const float* bi = b0 + ii * kD;
        #pragma unroll
        for (int mt = 0; mt < 2; ++mt) {
            const int jj = (pb & 511) + mt * 16 + c;
            const float* bj = b0 + jj * kD;
            #pragma unroll
            for (int s = 0; s < 2; ++s) {
                const int d0 = s * 32 + q * 8;
                float4 a0 = *(const float4*)(bj + d0);
                float4 a1v = *(const float4*)(bj + d0 + 4);
                float4 c0 = *(const float4*)(bi + d0);
                float4 c1v = *(const float4*)(bi + d0 + 4);
                Bf[mt][s] = mkh8(pkh(a0.x - c0.x, a0.y - c0.y),
                                 pkh(a0.z - c0.z, a0.w - c0.w),
                                 pkh(a1v.x - c1v.x, a1v.y - c1v.y),
                                 pkh(a1v.z - c1v.z, a1v.w - c1v.w));
            }
        }
    } else {
        #pragma unroll
        for (int mt = 0; mt < 2; ++mt) {
            #pragma unroll
            for (int s = 0; s < 2; ++s) {
                Bf[mt][s] = *(const f16x8*)(bias + (long)(pb + mt * 16 + c) * kD + s * 32 + q * 8);
            }
        }
    }

    {
        bf16x8 r0 = *(const bf16x8*)g_w1;
        bf16x8 r1 = *(const bf16x8*)g_w2;
        *(bf16x8*)&s_w[0][w1_dst] = r0;
        *(bf16x8*)&s_w[0][w2_dst] = r1;
        s_db[t] = diff_b[t];
        s_db[256 + t] = diff_b[256 + t];
        if (t < 2 * kD) s_x[t] = x[(blockIdx.x >> 3) * 2 * kD + t];
    }
    __syncthreads();

    // ---- fused qkv: 2 rows x 192 cols; independent of the g2 loop below.
    if (t < 192) {
        const int row0 = (blockIdx.x >> 3) * 2;
        const int cc = (blockIdx.x & 7) * 192 + t;
        float a0 = qb[cc];
        float a1 = a0;
        #pragma unroll 8
        for (int k = 0; k < kD; ++k) {
            float wv = qW[k * (3 * kHHD) + cc];
            a0 = fmaf(s_x[k], wv, a0);
            a1 = fmaf(s_x[kD + k], wv, a1);
        }
        qkv[row0 * (3 * kHHD) + cc] = a0;
        qkv[(row0 + 1) * (3 * kHHD) + cc] = a1;
    }

    f32x4 acc2[2][4];
    #pragma unroll
    for (int mt = 0; mt < 2; ++mt)
        #pragma unroll
        for (int dg = 0; dg < 4; ++dg) acc2[mt][dg] = (f32x4)0.0f;
    f32x2 psum2[2][4];
    #pragma unroll
    for (int mt = 0; mt < 2; ++mt)
        #pragma unroll
        for (int h = 0; h < 4; ++h) psum2[mt][h] = (f32x2)0.0f;

    const int sw1 = c & 7;
    const int sw2 = (c >> 1) & 3;
    int cur = 0;

    for (int g2 = 0; g2 < 16; ++g2) {
        bf16x8 r0, r1;
        if (g2 < 15) {
            r0 = *(const bf16x8*)(g_w1 + (g2 + 1) * 2048);
            r1 = *(const bf16x8*)(g_w2 + (g2 + 1) * 32);
        }

        // ---- GEMM1 with C initialized to diff_b
        const f32x4 db4l = *(const f32x4*)&s_db[g2 * 32 + q * 8];      // u=0
        const f32x4 db4h = *(const f32x4*)&s_db[g2 * 32 + q * 8 + 4];  // u=1
        f32x4 a1[2][2];
        #pragma unroll
        for (int mt = 0; mt < 2; ++mt) {
            a1[mt][0] = db4l;
            a1[mt][1] = db4h;
        }
        const u16* w1 = &s_w[cur][0];
        #pragma unroll
        for (int u = 0; u < 2; ++u) {
            int row = (u * 16 + c) * 64;
            int o0 = row + ((0 + q) ^ sw1) * 8;
            int o1 = row + ((4 + q) ^ sw1) * 8;
            f16x8 A0 = *(const f16x8*)(w1 + o0);
            f16x8 A1 = *(const f16x8*)(w1 + o1);
            #pragma unroll
            for (int mt = 0; mt < 2; ++mt) {
                a1[mt][u] = __builtin_amdgcn_mfma_f32_16x16x32_f16(A0, Bf[mt][0], a1[mt][u], 0, 0, 0);
                a1[mt][u] = __builtin_amdgcn_mfma_f32_16x16x32_f16(A1, Bf[mt][1], a1[mt][u], 0, 0, 0);
            }
        }

        // ---- mish + psum + fp16 pack (packed-fp32 pairs; db already in a1)
        const int hd = g2 >> 2;
        f16x8 A2[2];
        #pragma unroll
        for (int mt = 0; mt < 2; ++mt) {
            u32 p[2][2];
            #pragma unroll
            for (int u = 0; u < 2; ++u) {
                f32x2 xlo = {a1[mt][u][0], a1[mt][u][1]};
                f32x2 xhi = {a1[mt][u][2], a1[mt][u][3]};
                f32x2 vlo = mish2(xlo);
                f32x2 vhi = mish2(xhi);
                psum2[mt][hd] = __builtin_elementwise_fma(vlo, vlo, psum2[mt][hd]);
                psum2[mt][hd] = __builtin_elementwise_fma(vhi, vhi, psum2[mt][hd]);
                p[u][0] = pkh(vlo[0], vlo[1]);
                p[u][1] = pkh(vhi[0], vhi[1]);
            }
            A2[mt] = mkh8(p[0][0], p[0][1], p[1][0], p[1][1]);
        }

        if (!last) {
            const u16* w2 = &s_w[cur][2048];
            const int kb2 = (q ^ sw2) * 8;
            #pragma unroll
            for (int dg = 0; dg < 4; ++dg) {
                int bo = dg * 512 + c * 32 + kb2;
                f16x8 Wf = *(const f16x8*)(w2 + bo);
                #pragma unroll
                for (int mt = 0; mt < 2; ++mt) {
                    acc2[mt][dg] = __builtin_amdgcn_mfma_f32_16x16x32_f16(A2[mt], Wf, acc2[mt][dg], 0, 0, 0);
                }
            }
        }

        if (g2 < 15) {
            int nb = cur ^ 1;
            *(bf16x8*)&s_w[nb][w1_dst] = r0;
            *(bf16x8*)&s_w[nb][w2_dst] = r1;
            __syncthreads();
            cur = nb;
        }
    }

    // ---- epilogue: bias tile in place (fp16) + diffs
    if (!last) {
        #pragma unroll
        for (int mt = 0; mt < 2; ++mt) {
            #pragma unroll
            for (int dg = 0; dg < 4; ++dg) {
                float bb = bout_b[dg * 16 + c];
                f32x2 bb2 = {bb, bb};
                f32x2 vlo = mish2(f32x2{acc2[mt][dg][0], acc2[mt][dg][1]} + bb2);
                f32x2 vhi = mish2(f32x2{acc2[mt][dg][2], acc2[mt][dg][3]} + bb2);
                const long rbase = (long)(pb + mt * 16 + 4 * q);
                bias[(rbase + 0) * kD + dg * 16 + c] = f16_bits(vlo[0]);
                bias[(rbase + 1) * kD + dg * 16 + c] = f16_bits(vlo[1]);
                bias[(rbase + 2) * kD + dg * 16 + c] = f16_bits(vhi[0]);
                bias[(rbase + 3) * kD + dg * 16 + c] = f16_bits(vhi[1]);
            }
        }
    }
    const int i  = blockIdx.x >> 2;
    const int jb = (blockIdx.x & 3) * 128 + w * 32;
    #pragma unroll
    for (int mt = 0; mt < 2; ++mt) {
        float psum[4];
        #pragma unroll
        for (int h = 0; h < 4; ++h) {
            psum[h] = psum2[mt][h][0] + psum2[mt][h][1];
            psum[h] += __shfl_xor(psum[h], 16);
            psum[h] += __shfl_xor(psum[h], 32);
        }
        float sv = (q == 0) ? psum[0] : (q == 1) ? psum[1]
                 : (q == 2) ? psum[2] : psum[3];
        diffs[q * (kN * kN) + i * kN + jb + mt * 16 + c] = sqrtf(sv);
    }
}

// ---------------- fused flash attention (split-m, exact) ----------------
// grid (16 n-tiles of 32 rows, 4 m-chunks of 128, 4 heads) = 256 blocks.
// 512 threads (8 waves = 2 waves/SIMD at 1 block/CU). K staged in 2 chunks
// of [128 cols][64 k] (stride 68); V in 2 chunks of [64 m][132 d]. Barrier
// count halved vs 32-wide chunks; LDS 50.5 KB (grid-limited occupancy).
__global__ __launch_bounds__(512) void flash_attn_kernel(
    const float* __restrict__ qkv, const float* __restrict__ diffs,
    float* __restrict__ part, float* __restrict__ ml)
{
    __shared__ float s_a[32 * 132];  // Q (QK phase), then P (PV phase)
    __shared__ float s_b[128 * 68];  // K chunks [128][68]; V chunks [64][132]

    const int t  = threadIdx.x;
    const int tx = t & 31;
    const int ty = t >> 5;          // 0..15
    const int r0 = ty * 2;          // rows r0, r0+1
    const int n0 = blockIdx.x * 32;
    const int mq = blockIdx.y;
    const int h  = blockIdx.z;
    const int m0 = mq * 128;

    // ---- stage Q (32 x 128) : 1024 float4 over 512 threads
    #pragma unroll
    for (int rep = 0; rep < 2; ++rep) {
        int f = rep * 512 + t;
        int row = f >> 5;
        int c4  = f & 31;
        *(float4*)&s_a[row * 132 + c4 * 4] =
            *(const float4*)&qkv[(n0 + row) * (3 * kHHD) + h * 384 + c4 * 4];
    }

    float acc[2][4];
    #pragma unroll
    for (int i = 0; i < 2; ++i)
        #pragma unroll
        for (int cc = 0; cc < 4; ++cc) acc[i][cc] = 0.0f;

    // ---- S = Q K^T, k-dim chunked by 64
    for (int db = 0; db < 2; ++db) {
        __syncthreads();
        #pragma unroll
        for (int rep = 0; rep < 4; ++rep) {
            int f = rep * 512 + t;       // 2048 float4
            int col = f >> 4;            // 0..127
            int c4  = f & 15;            // 0..15
            *(float4*)&s_b[col * 68 + c4 * 4] =
                *(const float4*)&qkv[(m0 + col) * (3 * kHHD) + h * 384 + 128 + db * 64 + c4 * 4];
        }
        __syncthreads();
        #pragma unroll
        for (int k4 = 0; k4 < 16; ++k4) {
            float4 a0 = *(const float4*)&s_a[(r0 + 0) * 132 + db * 64 + k4 * 4];
            float4 a1 = *(const float4*)&s_a[(r0 + 1) * 132 + db * 64 + k4 * 4];
            #pragma unroll
            for (int cc = 0; cc < 4; ++cc) {
                float4 b = *(const float4*)&s_b[(tx + 32 * cc) * 68 + k4 * 4];
                acc[0][cc] = dot4(a0, b, acc[0][cc]);
                acc[1][cc] = dot4(a1, b, acc[1][cc]);
            }
        }
    }

    // ---- logits = S*scale + diffs; per-row softmax partial over 128 cols
    float mr[2], lr[2];
    #pragma unroll
    for (int i = 0; i < 2; ++i) {
        const float* dro = diffs + h * (kN * kN) + (n0 + r0 + i) * kN + m0 + tx;
        #pragma unroll
        for (int cc = 0; cc < 4; ++cc)
            acc[i][cc] = fmaf(acc[i][cc], kScale, dro[32 * cc]);
        float m = fmaxf(fmaxf(acc[i][0], acc[i][1]), fmaxf(acc[i][2], acc[i][3]));
        #pragma unroll
        for (int off = 1; off < 32; off <<= 1) m = fmaxf(m, __shfl_xor(m, off));
        mr[i] = m;
        float l = 0.0f;
        #pragma unroll
        for (int cc = 0; cc < 4; ++cc) {
            float p = __expf(acc[i][cc] - m);
            acc[i][cc] = p;
            l += p;
        }
        #pragma unroll
        for (int off = 1; off < 32; off <<= 1) l += __shfl_xor(l, off);
        lr[i] = l;
    }

    __syncthreads();   // all QK reads of s_a/s_b complete before overwrite
    #pragma unroll
    for (int i = 0; i < 2; ++i) {
        #pragma unroll
        for (int cc = 0; cc < 4; ++cc)
            s_a[(r0 + i) * 132 + tx + 32 * cc] = acc[i][cc];
        if (tx == 0)
            *(float2*)&ml[((h * 4 + mq) * kN + n0 + r0 + i) * 2] = make_float2(mr[i], lr[i]);
    }

    // ---- part = P V, m chunked by 64; V staged [m][d] (float4 reads)
    float4 o0 = {0,0,0,0}, o1 = {0,0,0,0};
    for (int ms = 0; ms < 2; ++ms) {
        if (ms > 0) __syncthreads();  // prior PV reads of s_b done
        #pragma unroll
        for (int rep = 0; rep < 4; ++rep) {
            int f = rep * 512 + t;       // 2048 float4
            int row = f >> 5;            // 0..63
            int c4  = f & 31;
            *(float4*)&s_b[row * 132 + c4 * 4] =
                *(const float4*)&qkv[(m0 + ms * 64 + row) * (3 * kHHD) + h * 384 + 256 + c4 * 4];
        }
        __syncthreads();  // V staged; (ms==0: P stores also visible)
        #pragma unroll
        for (int k4 = 0; k4 < 16; ++k4) {
            float4 p0 = *(const float4*)&s_a[(r0 + 0) * 132 + ms * 64 + k4 * 4];
            float4 p1 = *(const float4*)&s_a[(r0 + 1) * 132 + ms * 64 + k4 * 4];
            #pragma unroll
            for (int u = 0; u < 4; ++u) {
                float4 v = *(const float4*)&s_b[(k4 * 4 + u) * 132 + tx * 4];
                float pu0 = (u == 0) ? p0.x : (u == 1) ? p0.y : (u == 2) ? p0.z : p0.w;
                float pu1 = (u == 0) ? p1.x : (u == 1) ? p1.y : (u == 2) ? p1.z : p1.w;
                o0 = fma4(pu0, v, o0);
                o1 = fma4(pu1, v, o1);
            }
        }
    }
    const int pbase = (h * 4 + mq) * (kN * kHD) + (n0 + r0) * kHD + 4 * tx;
    *(float4*)&part[pbase]       = o0;
    *(float4*)&part[pbase + kHD] = o1;
}

// ---------------- x = LN2(x + combine(part)@o_W + o_b) [+ final] ----------
__global__ __launch_bounds__(256) void oproj_ln_kernel(
    const float* __restrict__ part, const float* __restrict__ ml,
    const float* __restrict__ o_W, const float* __restrict__ o_b,
    const float* __restrict__ g2, const float* __restrict__ b2,
    float* __restrict__ x,
    const float* __restrict__ out_W, const float* __restrict__ out_b,
    float* __restrict__ out, int dofinal)
{
    const int n = blockIdx.x;
    const int t = threadIdx.x;
    const int w = t >> 6;
    const int d = t & 63;
    __shared__ float s_v[kHHD];
    __shared__ float s_part[4][kD];
    #pragma unroll
    for (int r = 0; r < 2; ++r) {
        int j  = r * 256 + t;
        int h  = j >> 7;
        int dd = j & 127;
        float2 m_l[4];
        float M = -1e30f;
        #pragma unroll
        for (int q = 0; q < 4; ++q) {
            m_l[q] = *(const float2*)&ml[((h * 4 + q) * kN + n) * 2];
            M = fmaxf(M, m_l[q].x);
        }
        float L = 0.0f, wq[4];
        #pragma unroll
        for (int q = 0; q < 4; ++q) {
            wq[q] = __expf(m_l[q].x - M);
            L = fmaf(wq[q], m_l[q].y, L);
        }
        float sv = 0.0f;
        #pragma unroll
        for (int q = 0; q < 4; ++q) {
            sv = fmaf(wq[q], part[(h * 4 + q) * (kN * kHD) + n * kHD + dd], sv);
        }
        s_v[j] = sv / L;
    }
    __syncthreads();
    float acc = 0.0f;
    #pragma unroll 4
    for (int j = 0; j < 128; ++j)
        acc = fmaf(s_v[w * 128 + j], o_W[(w * 128 + j) * kD + d], acc);
    s_part[w][d] = acc;
    __syncthreads();
    if (t < kD) {
        float av = o_b[d] + ((s_part[0][d] + s_part[1][d]) + (s_part[2][d] + s_part[3][d]));
        float xv = x[n * kD + d] + av;
        float mu = xv;
        #pragma unroll
        for (int off = 32; off > 0; off >>= 1) mu += __shfl_xor(mu, off);
        mu *= (1.0f / kD);
        float dv = xv - mu;
        float var = dv * dv;
        #pragma unroll
        for (int off = 32; off > 0; off >>= 1) var += __shfl_xor(var, off);
        var *= (1.0f / kD);
        float xnew = dv * rsqrtf(var + kEps) * g2[d] + b2[d];
        x[n * kD + d] = xnew;
        if (dofinal) {
            float p = xnew * out_W[d];
            #pragma unroll
            for (int off = 32; off > 0; off >>= 1) p += __shfl_xor(p, off);
            if (d == 0) out[n] = p + out_b[0];
        }
    }
}

} // anonymous namespace

extern "C" void kernel_launch(void* const* d_in, const int* in_sizes, int n_in,
                              void* d_out, int out_size, void* d_ws, size_t ws_size,
                              hipStream_t stream)
{
    (void)in_sizes; (void)n_in; (void)out_size; (void)ws_size;

    const float* nf     = (const float*)d_in[0];
    const float* amds   = (const float*)d_in[1];
    const float* emb_W  = (const float*)d_in[2];
    const float* emb_b  = (const float*)d_in[3];
    const float* bemb_W = (const float*)d_in[4];
    const float* bemb_b = (const float*)d_in[5];
    const float* ln1_g  = (const float*)d_in[6];
    const float* ln1_b  = (const float*)d_in[7];
    const float* ln2_g  = (const float*)d_in[8];
    const float* ln2_b  = (const float*)d_in[9];
    const float* qkv_W  = (const float*)d_in[10];
    const float* qkv_b  = (const float*)d_in[11];
    const float* diff_W = (const float*)d_in[12];
    const float* diff_b = (const float*)d_in[13];
    const float* o_W    = (const float*)d_in[14];
    const float* o_b    = (const float*)d_in[15];
    const float* bout_W = (const float*)d_in[16];
    const float* bout_b = (const float*)d_in[17];
    const float* out_W  = (const float*)d_in[18];
    const float* out_b  = (const float*)d_in[19];

    float* ws = (float*)d_ws;
    float* ws_x      = ws;                   // 512*64
    float* ws_b0     = ws_x + 32768;         // 512*64
    float* ws_qkv    = ws_b0 + 32768;        // 512*1536
    float* ws_ml     = ws_qkv + 786432;      // (m,l) pairs: 4h*4mq*512*2
    float* ws_diffs  = ws_ml + 262144;       // 4*512*512 (diffs)
    float* ws_part   = ws_diffs + 1048576;   // 4h*4mq*512*128 fp32 = 4 MB
    u16*   ws_bias   = (u16*)(ws_part + 1048576); // 512*512*64 fp16 (33.5 MB)
    u16*   dWt       = ws_bias + 16777216;   // 4*512*64  fp16
    u16*   boutWt    = dWt + 131072;         // 4*64*512  fp16

    setup_kernel<<<1536, 256, 0, stream>>>(
        nf, amds, emb_W, emb_b, bemb_W, bemb_b, ln1_g, ln1_b, ws_x, ws_b0,
        diff_W, bout_W, dWt, boutWt);

    for (int l = 0; l < 4; ++l) {
        bias_layer_mfma<<<kN * kN / 128, 256, 0, stream>>>(
            ws_bias, dWt + l * 32768, boutWt + l * 32768,
            diff_b + l * kHHD, bout_b + l * kD, ws_b0, ws_diffs,
            ws_x, qkv_W + l * kD * (3 * kHHD), qkv_b + l * (3 * kHHD), ws_qkv,
            (l == 3) ? 1 : 0, (l == 0) ? 1 : 0);
        flash_attn_kernel<<<dim3(16, 4, kH), 512, 0, stream>>>(
            ws_qkv, ws_diffs, ws_part, ws_ml);
        oproj_ln_kernel<<<kN, 256, 0, stream>>>(
            ws_part, ws_ml, o_W + l * kHHD * kD, o_b + l * kD, ln2_g, ln2_b, ws_x,
            out_W, out_b, (float*)d_out, (l == 3) ? 1 : 0);
    }
}

// Round 13
// 473.254 us; speedup vs baseline: 1.1551x; 1.0212x over previous
//
#include <hip/hip_runtime.h>
#include <hip/hip_bf16.h>
#include <hip/hip_fp16.h>
#include <cmath>

// CrAKN fused implementation.
// R22 = R19 (best measured, 474.8us) + R21's setup merge only.
// R21 post-mortem: the flash 64-wide K/V chunking regressed (+8.5us total;
// bias unchanged at ~81.6 -> regression localizes to flash): longer
// unsynchronized phases reduced inter-wave overlap at 2 waves/SIMD.
// This round: flash reverted to R19's 32-wide chunks verbatim; setup_kernel
// merge (embed+prep, -1 dispatch) kept.

namespace {

constexpr int kN   = 512;
constexpr int kD   = 64;
constexpr int kH   = 4;
constexpr int kHD  = 128;
constexpr int kHHD = 512;
constexpr int kFB  = 256;
constexpr int kK   = 100;
constexpr float kEps   = 1e-5f;
constexpr float kScale = 0.08838834764831845f; // 1/sqrt(128)

typedef unsigned short u16;
typedef unsigned int u32;
typedef short bf16x8 __attribute__((ext_vector_type(8)));   // raw 16B container
typedef _Float16 f16x8 __attribute__((ext_vector_type(8)));
typedef float f32x4 __attribute__((ext_vector_type(4)));
typedef float f32x2 __attribute__((ext_vector_type(2)));

// packed-pair mish: identical math per lane; non-trans ops on f32x2 so the
// compiler can select v_pk_add_f32 / v_pk_fma_f32 (VOP3P, gfx90a+).
__device__ __forceinline__ f32x2 mish2(f32x2 x) {
    float e0 = __expf(x[0]);
    float e1 = __expf(x[1]);
    f32x2 e  = {e0, e1};
    f32x2 n2 = __builtin_elementwise_fma(e, e + 2.0f, (f32x2)(2.0f));
    f32x2 r  = {__builtin_amdgcn_rcpf(n2[0]), __builtin_amdgcn_rcpf(n2[1])};
    return __builtin_elementwise_fma(x + x, -r, x);
}

__device__ __forceinline__ u32 pkh(float a, float b) {
    union { __half2 h; u32 u; } cv;
    cv.h = __float22half2_rn(make_float2(a, b));
    return cv.u; // a low 16, b high 16
}
__device__ __forceinline__ f16x8 mkh8(u32 a, u32 b, u32 c, u32 d) {
    union { u32 w[4]; f16x8 v; } cv;
    cv.w[0] = a; cv.w[1] = b; cv.w[2] = c; cv.w[3] = d;
    return cv.v;
}
__device__ __forceinline__ u16 f16_bits(float f) {
    union { __half h; u16 u; } cv;
    cv.h = __float2half(f);
    return cv.u;
}

__device__ __forceinline__ float dot4(float4 a, float4 b, float acc) {
    acc = fmaf(a.x, b.x, acc);
    acc = fmaf(a.y, b.y, acc);
    acc = fmaf(a.z, b.z, acc);
    acc = fmaf(a.w, b.w, acc);
    return acc;
}
__device__ __forceinline__ float4 fma4(float s, float4 v, float4 d) {
    d.x = fmaf(s, v.x, d.x);
    d.y = fmaf(s, v.y, d.y);
    d.z = fmaf(s, v.z, d.z);
    d.w = fmaf(s, v.w, d.w);
    return d;
}

// ---------------- setup: embed+LN1, b0, weight transpose+fp16 ----------------
// blocks [0,512): embed row n (256 threads; barriers block-uniform).
// blocks [512,1536): weight prep.
__global__ __launch_bounds__(256) void setup_kernel(
    const float* __restrict__ nf, const float* __restrict__ amds,
    const float* __restrict__ emb_W, const float* __restrict__ emb_b,
    const float* __restrict__ bemb_W, const float* __restrict__ bemb_b,
    const float* __restrict__ ln1_g, const float* __restrict__ ln1_b,
    float* __restrict__ x, float* __restrict__ b0,
    const float* __restrict__ diff_W, const float* __restrict__ bout_W,
    u16* __restrict__ dWt, u16* __restrict__ boutWt)
{
    const int t = threadIdx.x;
    if (blockIdx.x >= 512) {
        int gid = (blockIdx.x - 512) * 256 + t; // 2 * 4 * 32768
        if (gid < 4 * 32768) {
            int e = gid;
            int l = e >> 15;
            int r = e & 32767;
            int k = r >> 9;
            int n = r & 511;
            dWt[l * 32768 + n * 64 + k] = f16_bits(diff_W[e]);
        } else {
            int e = gid - 4 * 32768;
            int l = e >> 15;
            int r = e & 32767;
            int k = r >> 6;
            int d = r & 63;
            boutWt[l * 32768 + d * 512 + k] = f16_bits(bout_W[e]);
        }
        return;
    }
    const int n = blockIdx.x;
    __shared__ float s_row[kFB];
    s_row[t] = nf[n * kFB + t];
    __syncthreads();
    if (t < kD) {
        const int d = t;
        float acc = emb_b[d];
        for (int k = 0; k < kFB; ++k) acc = fmaf(s_row[k], emb_W[k * kD + d], acc);
        float mu = acc;
        #pragma unroll
        for (int off = 32; off > 0; off >>= 1) mu += __shfl_xor(mu, off);
        mu *= (1.0f / kD);
        float dv = acc - mu;
        float var = dv * dv;
        #pragma unroll
        for (int off = 32; off > 0; off >>= 1) var += __shfl_xor(var, off);
        var *= (1.0f / kD);
        x[n * kD + d] = dv * rsqrtf(var + kEps) * ln1_g[d] + ln1_b[d];
    }
    __syncthreads();
    if (t < kK) s_row[t] = amds[n * kK + t];
    __syncthreads();
    if (t < kD) {
        const int d = t;
        float bacc = bemb_b[d];
        for (int k = 0; k < kK; ++k) bacc = fmaf(s_row[k], bemb_W[k * kD + d], bacc);
        b0[n * kD + d] = bacc;
    }
}

// ---------------- fused pair-bias chain, fp16 MFMA + qkv prologue ----------
// R16 structure (4 waves x 32 pairs, 256 thr, packed-fp32 mish/psum) +
// first-layer Bf from b0 + db-as-accumulator-init + fused qkv for this layer.
__global__ __launch_bounds__(256, 2) void bias_layer_mfma(
    u16* __restrict__ bias,
    const u16* __restrict__ dWt, const u16* __restrict__ boutWt,
    const float* __restrict__ diff_b, const float* __restrict__ bout_b,
    const float* __restrict__ b0, float* __restrict__ diffs,
    const float* __restrict__ x, const float* __restrict__ qW,
    const float* __restrict__ qb, float* __restrict__ qkv,
    int last, int first)
{
    // [buf][ w1: 32 rows * 64 u16 | w2 at 2048: 64 rows * 32 u16 ]
    __shared__ u16 s_w[2][4096]; // 16 KB
    __shared__ float s_db[kHHD]; // 2 KB, broadcast-read per g2
    __shared__ float s_x[2 * kD]; // 512 B, fused-qkv x rows

    const int t    = threadIdx.x;
    const int w    = t >> 6;
    const int lane = t & 63;
    const int q    = lane >> 4;    // quad
    const int c    = lane & 15;
    const int pb   = blockIdx.x * 128 + w * 32;  // wave's 32 pairs

    const int sb_bc  = t >> 3;
    const int sb_kb  = t & 7;
    const int sr     = ((sb_bc >> 2) & 1) * 16 + ((sb_bc >> 3) << 2) + (sb_bc & 3);
    const int w1_dst = sr * 64 + (sb_kb ^ (sr & 7)) * 8;
    const int sb_d   = t >> 2;
    const int sb_k2  = t & 3;
    const int w2_dst = 2048 + sb_d * 32 + (sb_k2 ^ ((sb_d >> 1) & 3)) * 8;
    const u16* g_w1 = dWt + sb_bc * 64 + sb_kb * 8;
    const u16* g_w2 = boutWt + sb_d * 512 + sb_k2 * 8;

    // --- B-frags: bias^T (fp16) for two 16-pair tiles, K=64.
    f16x8 Bf[2][2];
    if (first) {
        const int ii = pb >> 9;                   // block-uniform i
        const float* bi = b0 + ii * kD;
        #pragma unroll
        for (int mt = 0; mt < 2; ++mt) {
            const int jj = (pb & 511) + mt * 16 + c;
            const float* bj = b0 + jj * kD;
            #pragma unroll
            for (int s = 0; s < 2; ++s) {
                const int d0 = s * 32 + q * 8;
                float4 a0 = *(const float4*)(bj + d0);
                float4 a1v = *(const float4*)(bj + d0 + 4);
                float4 c0 = *(const float4*)(bi + d0);
                float4 c1v = *(const float4*)(bi + d0 + 4);
                Bf[mt][s] = mkh8(pkh(a0.x - c0.x, a0.y - c0.y),
                                 pkh(a0.z - c0.z, a0.w - c0.w),
                                 pkh(a1v.x - c1v.x, a1v.y - c1v.y),
                                 pkh(a1v.z - c1v.z, a1v.w - c1v.w));
            }
        }
    } else {
        #pragma unroll
        for (int mt = 0; mt < 2; ++mt) {
            #pragma unroll
            for (int s = 0; s < 2; ++s) {
                Bf[mt][s] = *(const f16x8*)(bias + (long)(pb + mt * 16 + c) * kD + s * 32 + q * 8);
            }
        }
    }

    {
        bf16x8 r0 = *(const bf16x8*)g_w1;
        bf16x8 r1 = *(const bf16x8*)g_w2;
        *(bf16x8*)&s_w[0][w1_dst] = r0;
        *(bf16x8*)&s_w[0][w2_dst] = r1;
        s_db[t] = diff_b[t];
        s_db[256 + t] = diff_b[256 + t];
        if (t < 2 * kD) s_x[t] = x[(blockIdx.x >> 3) * 2 * kD + t];
    }
    __syncthreads();

    // ---- fused qkv: 2 rows x 192 cols; independent of the g2 loop below.
    if (t < 192) {
        const int row0 = (blockIdx.x >> 3) * 2;
        const int cc = (blockIdx.x & 7) * 192 + t;
        float a0 = qb[cc];
        float a1 = a0;
        #pragma unroll 8
        for (int k = 0; k < kD; ++k) {
            float wv = qW[k * (3 * kHHD) + cc];
            a0 = fmaf(s_x[k], wv, a0);
            a1 = fmaf(s_x[kD + k], wv, a1);
        }
        qkv[row0 * (3 * kHHD) + cc] = a0;
        qkv[(row0 + 1) * (3 * kHHD) + cc] = a1;
    }

    f32x4 acc2[2][4];
    #pragma unroll
    for (int mt = 0; mt < 2; ++mt)
        #pragma unroll
        for (int dg = 0; dg < 4; ++dg) acc2[mt][dg] = (f32x4)0.0f;
    f32x2 psum2[2][4];
    #pragma unroll
    for (int mt = 0; mt < 2; ++mt)
        #pragma unroll
        for (int h = 0; h < 4; ++h) psum2[mt][h] = (f32x2)0.0f;

    const int sw1 = c & 7;
    const int sw2 = (c >> 1) & 3;
    int cur = 0;

    for (int g2 = 0; g2 < 16; ++g2) {
        bf16x8 r0, r1;
        if (g2 < 15) {
            r0 = *(const bf16x8*)(g_w1 + (g2 + 1) * 2048);
            r1 = *(const bf16x8*)(g_w2 + (g2 + 1) * 32);
        }

        // ---- GEMM1 with C initialized to diff_b
        const f32x4 db4l = *(const f32x4*)&s_db[g2 * 32 + q * 8];      // u=0
        const f32x4 db4h = *(const f32x4*)&s_db[g2 * 32 + q * 8 + 4];  // u=1
        f32x4 a1[2][2];
        #pragma unroll
        for (int mt = 0; mt < 2; ++mt) {
            a1[mt][0] = db4l;
            a1[mt][1] = db4h;
        }
        const u16* w1 = &s_w[cur][0];
        #pragma unroll
        for (int u = 0; u < 2; ++u) {
            int row = (u * 16 + c) * 64;
            int o0 = row + ((0 + q) ^ sw1) * 8;
            int o1 = row + ((4 + q) ^ sw1) * 8;
            f16x8 A0 = *(const f16x8*)(w1 + o0);
            f16x8 A1 = *(const f16x8*)(w1 + o1);
            #pragma unroll
            for (int mt = 0; mt < 2; ++mt) {
                a1[mt][u] = __builtin_amdgcn_mfma_f32_16x16x32_f16(A0, Bf[mt][0], a1[mt][u], 0, 0, 0);
                a1[mt][u] = __builtin_amdgcn_mfma_f32_16x16x32_f16(A1, Bf[mt][1], a1[mt][u], 0, 0, 0);
            }
        }

        // ---- mish + psum + fp16 pack (packed-fp32 pairs; db already in a1)
        const int hd = g2 >> 2;
        f16x8 A2[2];
        #pragma unroll
        for (int mt = 0; mt < 2; ++mt) {
            u32 p[2][2];
            #pragma unroll
            for (int u = 0; u < 2; ++u) {
                f32x2 xlo = {a1[mt][u][0], a1[mt][u][1]};
                f32x2 xhi = {a1[mt][u][2], a1[mt][u][3]};
                f32x2 vlo = mish2(xlo);
                f32x2 vhi = mish2(xhi);
                psum2[mt][hd] = __builtin_elementwise_fma(vlo, vlo, psum2[mt][hd]);
                psum2[mt][hd] = __builtin_elementwise_fma(vhi, vhi, psum2[mt][hd]);
                p[u][0] = pkh(vlo[0], vlo[1]);
                p[u][1] = pkh(vhi[0], vhi[1]);
            }
            A2[mt] = mkh8(p[0][0], p[0][1], p[1][0], p[1][1]);
        }

        if (!last) {
            const u16* w2 = &s_w[cur][2048];
            const int kb2 = (q ^ sw2) * 8;
            #pragma unroll
            for (int dg = 0; dg < 4; ++dg) {
                int bo = dg * 512 + c * 32 + kb2;
                f16x8 Wf = *(const f16x8*)(w2 + bo);
                #pragma unroll
                for (int mt = 0; mt < 2; ++mt) {
                    acc2[mt][dg] = __builtin_amdgcn_mfma_f32_16x16x32_f16(A2[mt], Wf, acc2[mt][dg], 0, 0, 0);
                }
            }
        }

        if (g2 < 15) {
            int nb = cur ^ 1;
            *(bf16x8*)&s_w[nb][w1_dst] = r0;
            *(bf16x8*)&s_w[nb][w2_dst] = r1;
            __syncthreads();
            cur = nb;
        }
    }

    // ---- epilogue: bias tile in place (fp16) + diffs
    if (!last) {
        #pragma unroll
        for (int mt = 0; mt < 2; ++mt) {
            #pragma unroll
            for (int dg = 0; dg < 4; ++dg) {
                float bb = bout_b[dg * 16 + c];
                f32x2 bb2 = {bb, bb};
                f32x2 vlo = mish2(f32x2{acc2[mt][dg][0], acc2[mt][dg][1]} + bb2);
                f32x2 vhi = mish2(f32x2{acc2[mt][dg][2], acc2[mt][dg][3]} + bb2);
                const long rbase = (long)(pb + mt * 16 + 4 * q);
                bias[(rbase + 0) * kD + dg * 16 + c] = f16_bits(vlo[0]);
                bias[(rbase + 1) * kD + dg * 16 + c] = f16_bits(vlo[1]);
                bias[(rbase + 2) * kD + dg * 16 + c] = f16_bits(vhi[0]);
                bias[(rbase + 3) * kD + dg * 16 + c] = f16_bits(vhi[1]);
            }
        }
    }
    const int i  = blockIdx.x >> 2;
    const int jb = (blockIdx.x & 3) * 128 + w * 32;
    #pragma unroll
    for (int mt = 0; mt < 2; ++mt) {
        float psum[4];
        #pragma unroll
        for (int h = 0; h < 4; ++h) {
            psum[h] = psum2[mt][h][0] + psum2[mt][h][1];
            psum[h] += __shfl_xor(psum[h], 16);
            psum[h] += __shfl_xor(psum[h], 32);
        }
        float sv = (q == 0) ? psum[0] : (q == 1) ? psum[1]
                 : (q == 2) ? psum[2] : psum[3];
        diffs[q * (kN * kN) + i * kN + jb + mt * 16 + c] = sqrtf(sv);
    }
}

// ---------------- fused flash attention (split-m, exact) ----------------
// grid (16 n-tiles of 32 rows, 4 m-chunks of 128, 4 heads) = 256 blocks.
// 512 threads (8 waves = 2 waves/SIMD at 1 block/CU). 32-wide K/V chunks
// (R19-verbatim; R21's 64-wide chunking regressed).
__global__ __launch_bounds__(512) void flash_attn_kernel(
    const float* __restrict__ qkv, const float* __restrict__ diffs,
    float* __restrict__ part, float* __restrict__ ml)
{
    __shared__ float s_a[32 * 132];  // Q (QK phase), then P (PV phase)
    __shared__ float s_b[128 * 36];  // K chunks [128][36]; V chunks [32][132]

    const int t  = threadIdx.x;
    const int tx = t & 31;
    const int ty = t >> 5;          // 0..15
    const int r0 = ty * 2;          // rows r0, r0+1
    const int n0 = blockIdx.x * 32;
    const int mq = blockIdx.y;
    const int h  = blockIdx.z;
    const int m0 = mq * 128;

    // ---- stage Q (32 x 128) : 1024 float4 over 512 threads
    #pragma unroll
    for (int rep = 0; rep < 2; ++rep) {
        int f = rep * 512 + t;
        int row = f >> 5;
        int c4  = f & 31;
        *(float4*)&s_a[row * 132 + c4 * 4] =
            *(const float4*)&qkv[(n0 + row) * (3 * kHHD) + h * 384 + c4 * 4];
    }

    float acc[2][4];
    #pragma unroll
    for (int i = 0; i < 2; ++i)
        #pragma unroll
        for (int cc = 0; cc < 4; ++cc) acc[i][cc] = 0.0f;

    // ---- S = Q K^T, k-dim chunked by 32
    for (int db = 0; db < 4; ++db) {
        __syncthreads();
        #pragma unroll
        for (int rep = 0; rep < 2; ++rep) {
            int f = rep * 512 + t;
            int col = f >> 3;
            int c4  = f & 7;
            *(float4*)&s_b[col * 36 + c4 * 4] =
                *(const float4*)&qkv[(m0 + col) * (3 * kHHD) + h * 384 + 128 + db * 32 + c4 * 4];
        }
        __syncthreads();
        #pragma unroll
        for (int k4 = 0; k4 < 8; ++k4) {
            float4 a0 = *(const float4*)&s_a[(r0 + 0) * 132 + db * 32 + k4 * 4];
            float4 a1 = *(const float4*)&s_a[(r0 + 1) * 132 + db * 32 + k4 * 4];
            #pragma unroll
            for (int cc = 0; cc < 4; ++cc) {
                float4 b = *(const float4*)&s_b[(tx + 32 * cc) * 36 + k4 * 4];
                acc[0][cc] = dot4(a0, b, acc[0][cc]);
                acc[1][cc] = dot4(a1, b, acc[1][cc]);
            }
        }
    }

    // ---- logits = S*scale + diffs; per-row softmax partial over 128 cols
    float mr[2], lr[2];
    #pragma unroll
    for (int i = 0; i < 2; ++i) {
        const float* dro = diffs + h * (kN * kN) + (n0 + r0 + i) * kN + m0 + tx;
        #pragma unroll
        for (int cc = 0; cc < 4; ++cc)
            acc[i][cc] = fmaf(acc[i][cc], kScale, dro[32 * cc]);
        float m = fmaxf(fmaxf(acc[i][0], acc[i][1]), fmaxf(acc[i][2], acc[i][3]));
        #pragma unroll
        for (int off = 1; off < 32; off <<= 1) m = fmaxf(m, __shfl_xor(m, off));
        mr[i] = m;
        float l = 0.0f;
        #pragma unroll
        for (int cc = 0; cc < 4; ++cc) {
            float p = __expf(acc[i][cc] - m);
            acc[i][cc] = p;
            l += p;
        }
        #pragma unroll
        for (int off = 1; off < 32; off <<= 1) l += __shfl_xor(l, off);
        lr[i] = l;
    }

    __syncthreads();   // all QK reads of s_a/s_b complete before overwrite
    #pragma unroll
    for (int i = 0; i < 2; ++i) {
        #pragma unroll
        for (int cc = 0; cc < 4; ++cc)
            s_a[(r0 + i) * 132 + tx + 32 * cc] = acc[i][cc];
        if (tx == 0)
            *(float2*)&ml[((h * 4 + mq) * kN + n0 + r0 + i) * 2] = make_float2(mr[i], lr[i]);
    }

    // ---- part = P V, m chunked by 32; V staged [m][d] (float4 reads)
    float4 o0 = {0,0,0,0}, o1 = {0,0,0,0};
    for (int ms = 0; ms < 4; ++ms) {
        if (ms > 0) __syncthreads();  // prior PV reads of s_b done
        #pragma unroll
        for (int rep = 0; rep < 2; ++rep) {
            int f = rep * 512 + t;
            int row = f >> 5;
            int c4  = f & 31;
            *(float4*)&s_b[row * 132 + c4 * 4] =
                *(const float4*)&qkv[(m0 + ms * 32 + row) * (3 * kHHD) + h * 384 + 256 + c4 * 4];
        }
        __syncthreads();  // V staged; (ms==0: P stores also visible)
        #pragma unroll
        for (int k4 = 0; k4 < 8; ++k4) {
            float4 p0 = *(const float4*)&s_a[(r0 + 0) * 132 + ms * 32 + k4 * 4];
            float4 p1 = *(const float4*)&s_a[(r0 + 1) * 132 + ms * 32 + k4 * 4];
            #pragma unroll
            for (int u = 0; u < 4; ++u) {
                float4 v = *(const float4*)&s_b[(k4 * 4 + u) * 132 + tx * 4];
                float pu0 = (u == 0) ? p0.x : (u == 1) ? p0.y : (u == 2) ? p0.z : p0.w;
                float pu1 = (u == 0) ? p1.x : (u == 1) ? p1.y : (u == 2) ? p1.z : p1.w;
                o0 = fma4(pu0, v, o0);
                o1 = fma4(pu1, v, o1);
            }
        }
    }
    const int pbase = (h * 4 + mq) * (kN * kHD) + (n0 + r0) * kHD + 4 * tx;
    *(float4*)&part[pbase]       = o0;
    *(float4*)&part[pbase + kHD] = o1;
}

// ---------------- x = LN2(x + combine(part)@o_W + o_b) [+ final] ----------
__global__ __launch_bounds__(256) void oproj_ln_kernel(
    const float* __restrict__ part, const float* __restrict__ ml,
    const float* __restrict__ o_W, const float* __restrict__ o_b,
    const float* __restrict__ g2, const float* __restrict__ b2,
    float* __restrict__ x,
    const float* __restrict__ out_W, const float* __restrict__ out_b,
    float* __restrict__ out, int dofinal)
{
    const int n = blockIdx.x;
    const int t = threadIdx.x;
    const int w = t >> 6;
    const int d = t & 63;
    __shared__ float s_v[kHHD];
    __shared__ float s_part[4][kD];
    #pragma unroll
    for (int r = 0; r < 2; ++r) {
        int j  = r * 256 + t;
        int h  = j >> 7;
        int dd = j & 127;
        float2 m_l[4];
        float M = -1e30f;
        #pragma unroll
        for (int q = 0; q < 4; ++q) {
            m_l[q] = *(const float2*)&ml[((h * 4 + q) * kN + n) * 2];
            M = fmaxf(M, m_l[q].x);
        }
        float L = 0.0f, wq[4];
        #pragma unroll
        for (int q = 0; q < 4; ++q) {
            wq[q] = __expf(m_l[q].x - M);
            L = fmaf(wq[q], m_l[q].y, L);
        }
        float sv = 0.0f;
        #pragma unroll
        for (int q = 0; q < 4; ++q) {
            sv = fmaf(wq[q], part[(h * 4 + q) * (kN * kHD) + n * kHD + dd], sv);
        }
        s_v[j] = sv / L;
    }
    __syncthreads();
    float acc = 0.0f;
    #pragma unroll 4
    for (int j = 0; j < 128; ++j)
        acc = fmaf(s_v[w * 128 + j], o_W[(w * 128 + j) * kD + d], acc);
    s_part[w][d] = acc;
    __syncthreads();
    if (t < kD) {
        float av = o_b[d] + ((s_part[0][d] + s_part[1][d]) + (s_part[2][d] + s_part[3][d]));
        float xv = x[n * kD + d] + av;
        float mu = xv;
        #pragma unroll
        for (int off = 32; off > 0; off >>= 1) mu += __shfl_xor(mu, off);
        mu *= (1.0f / kD);
        float dv = xv - mu;
        float var = dv * dv;
        #pragma unroll
        for (int off = 32; off > 0; off >>= 1) var += __shfl_xor(var, off);
        var *= (1.0f / kD);
        float xnew = dv * rsqrtf(var + kEps) * g2[d] + b2[d];
        x[n * kD + d] = xnew;
        if (dofinal) {
            float p = xnew * out_W[d];
            #pragma unroll
            for (int off = 32; off > 0; off >>= 1) p += __shfl_xor(p, off);
            if (d == 0) out[n] = p + out_b[0];
        }
    }
}

} // anonymous namespace

extern "C" void kernel_launch(void* const* d_in, const int* in_sizes, int n_in,
                              void* d_out, int out_size, void* d_ws, size_t ws_size,
                              hipStream_t stream)
{
    (void)in_sizes; (void)n_in; (void)out_size; (void)ws_size;

    const float* nf     = (const float*)d_in[0];
    const float* amds   = (const float*)d_in[1];
    const float* emb_W  = (const float*)d_in[2];
    const float* emb_b  = (const float*)d_in[3];
    const float* bemb_W = (const float*)d_in[4];
    const float* bemb_b = (const float*)d_in[5];
    const float* ln1_g  = (const float*)d_in[6];
    const float* ln1_b  = (const float*)d_in[7];
    const float* ln2_g  = (const float*)d_in[8];
    const float* ln2_b  = (const float*)d_in[9];
    const float* qkv_W  = (const float*)d_in[10];
    const float* qkv_b  = (const float*)d_in[11];
    const float* diff_W = (const float*)d_in[12];
    const float* diff_b = (const float*)d_in[13];
    const float* o_W    = (const float*)d_in[14];
    const float* o_b    = (const float*)d_in[15];
    const float* bout_W = (const float*)d_in[16];
    const float* bout_b = (const float*)d_in[17];
    const float* out_W  = (const float*)d_in[18];
    const float* out_b  = (const float*)d_in[19];

    float* ws = (float*)d_ws;
    float* ws_x      = ws;                   // 512*64
    float* ws_b0     = ws_x + 32768;         // 512*64
    float* ws_qkv    = ws_b0 + 32768;        // 512*1536
    float* ws_ml     = ws_qkv + 786432;      // (m,l) pairs: 4h*4mq*512*2
    float* ws_diffs  = ws_ml + 262144;       // 4*512*512 (diffs)
    float* ws_part   = ws_diffs + 1048576;   // 4h*4mq*512*128 fp32 = 4 MB
    u16*   ws_bias   = (u16*)(ws_part + 1048576); // 512*512*64 fp16 (33.5 MB)
    u16*   dWt       = ws_bias + 16777216;   // 4*512*64  fp16
    u16*   boutWt    = dWt + 131072;         // 4*64*512  fp16

    setup_kernel<<<1536, 256, 0, stream>>>(
        nf, amds, emb_W, emb_b, bemb_W, bemb_b, ln1_g, ln1_b, ws_x, ws_b0,
        diff_W, bout_W, dWt, boutWt);

    for (int l = 0; l < 4; ++l) {
        bias_layer_mfma<<<kN * kN / 128, 256, 0, stream>>>(
            ws_bias, dWt + l * 32768, boutWt + l * 32768,
            diff_b + l * kHHD, bout_b + l * kD, ws_b0, ws_diffs,
            ws_x, qkv_W + l * kD * (3 * kHHD), qkv_b + l * (3 * kHHD), ws_qkv,
            (l == 3) ? 1 : 0, (l == 0) ? 1 : 0);
        flash_attn_kernel<<<dim3(16, 4, kH), 512, 0, stream>>>(
            ws_qkv, ws_diffs, ws_part, ws_ml);
        oproj_ln_kernel<<<kN, 256, 0, stream>>>(
            ws_part, ws_ml, o_W + l * kHHD * kD, o_b + l * kD, ln2_g, ln2_b, ws_x,
            out_W, out_b, (float*)d_out, (l == 3) ? 1 : 0);
    }
}